// Round 7
// baseline (172.848 us; speedup 1.0000x reference)
//
#include <hip/hip_runtime.h>
#include <cstdint>

#define MDIM 2048
#define KDIM 1024
#define CDIM 8192
#define BM 128
#define BN 128
#define BK 32
#define SROW 40   // shorts per padded LDS row: 32 bf16 data + 8 pad = 80 B (16B-aligned; ≤2-way banks)
#define NCHUNK (2 * (CDIM / BN))   // 128 partial chunks of 64 cols each

typedef __attribute__((ext_vector_type(8))) __bf16 bf16x8;
typedef __attribute__((ext_vector_type(4))) float f32x4;
typedef __attribute__((ext_vector_type(8))) unsigned short u16x8;

// ---------- helpers ----------
__device__ __forceinline__ unsigned short f2bf_rna(float f) {
  return (unsigned short)((__float_as_uint(f) + 0x8000u) >> 16);  // round-half-away
}

__device__ __forceinline__ u16x8 pack_bf16(float4 a, float4 b) {
  u16x8 r;
  r[0] = f2bf_rna(a.x); r[1] = f2bf_rna(a.y); r[2] = f2bf_rna(a.z); r[3] = f2bf_rna(a.w);
  r[4] = f2bf_rna(b.x); r[5] = f2bf_rna(b.y); r[6] = f2bf_rna(b.z); r[7] = f2bf_rna(b.w);
  return r;
}

// ---------- K1: fused fp32->bf16 VGPR-staged MFMA GEMM + per-64col softmax/argmax ----------
// Pipeline per k-iter: [cvt+ds_write tile k] barrier [issue global loads k+1]
// [ds_read frags k; MFMA k] barrier — prefetch latency overlaps MFMA instead of
// being drained by the barrier (the R2..R6 global_load_lds structure stalled
// ~2.4K cyc/iter on vmcnt(0) at 4-blocks/CU grid-capped occupancy).
__global__ __launch_bounds__(256) void gemm_fused(
    const float* __restrict__ X, const float* __restrict__ Cf,
    float* __restrict__ pm, float* __restrict__ pl, int* __restrict__ pidx) {
  __shared__ __align__(16) unsigned short As[BM * SROW];
  __shared__ __align__(16) unsigned short Bs[BN * SROW];
  __shared__ float c2s[BN];
  const int tid = threadIdx.x;
  const int wave = tid >> 6, lane = tid & 63;
  const int wm = wave >> 1, wn = wave & 1;
  const int bn = blockIdx.x, bm = blockIdx.y;
  const int quad = lane >> 4, c16 = lane & 15;

  // staging map: thread -> (row 0..127, k-half of 16 floats)
  const int sr = tid >> 1;
  const int sh = tid & 1;
  const float* ag = X  + (size_t)(bm * BM + sr) * KDIM + sh * 16;
  const float* bg = Cf + (size_t)(bn * BN + sr) * KDIM + sh * 16;
  unsigned short* aw = &As[sr * SROW + sh * 16];
  unsigned short* bw = &Bs[sr * SROW + sh * 16];

  f32x4 acc[4][4] = {};
  float sq = 0.f;

  float4 av[4], bv[4];
#pragma unroll
  for (int j = 0; j < 4; ++j) { av[j] = ((const float4*)ag)[j]; bv[j] = ((const float4*)bg)[j]; }

  for (int k0 = 0; k0 < KDIM; k0 += BK) {
    // c2 partial from the fp32 values (exact, before conversion)
#pragma unroll
    for (int j = 0; j < 4; ++j)
      sq += bv[j].x * bv[j].x + bv[j].y * bv[j].y + bv[j].z * bv[j].z + bv[j].w * bv[j].w;
    // convert + write tile k to LDS (2x ds_write_b128 per array)
    *(u16x8*)(aw)     = pack_bf16(av[0], av[1]);
    *(u16x8*)(aw + 8) = pack_bf16(av[2], av[3]);
    *(u16x8*)(bw)     = pack_bf16(bv[0], bv[1]);
    *(u16x8*)(bw + 8) = pack_bf16(bv[2], bv[3]);
    __syncthreads();   // LDS tile k ready

    // prefetch tile k+1 into VGPRs — overlaps the MFMA below
    if (k0 + BK < KDIM) {
      const float* an = ag + k0 + BK;
      const float* bnx = bg + k0 + BK;
#pragma unroll
      for (int j = 0; j < 4; ++j) { av[j] = ((const float4*)an)[j]; bv[j] = ((const float4*)bnx)[j]; }
    }

    bf16x8 a[4], b[4];
#pragma unroll
    for (int mt = 0; mt < 4; ++mt)
      a[mt] = *(const bf16x8*)&As[(wm * 64 + mt * 16 + c16) * SROW + quad * 8];
#pragma unroll
    for (int nt = 0; nt < 4; ++nt)
      b[nt] = *(const bf16x8*)&Bs[(wn * 64 + nt * 16 + c16) * SROW + quad * 8];
#pragma unroll
    for (int mt = 0; mt < 4; ++mt)
#pragma unroll
      for (int nt = 0; nt < 4; ++nt)
        acc[mt][nt] = __builtin_amdgcn_mfma_f32_16x16x32_bf16(a[mt], b[nt], acc[mt][nt], 0, 0, 0);
    __syncthreads();   // done reading LDS tile k
  }

  // publish c2 for this block's 128 columns: pair (sh=0,1) -> full K sum
  sq += __shfl_xor(sq, 1, 64);
  if (sh == 0) c2s[sr] = sq;
  __syncthreads();

  // Epilogue (max-first, exp-light): C/D layout col=lane&15, row=quad*4+reg.
  const int colbase = bn * BN + wn * 64;
  float c2v[4];
#pragma unroll
  for (int nt = 0; nt < 4; ++nt) c2v[nt] = c2s[wn * 64 + nt * 16 + c16];

  const int chunk = bn * 2 + wn;
#pragma unroll
  for (int mt = 0; mt < 4; ++mt) {
#pragma unroll
    for (int r = 0; r < 4; ++r) {
      float sv[4];
#pragma unroll
      for (int nt = 0; nt < 4; ++nt) sv[nt] = 2.0f * acc[mt][nt][r] - c2v[nt];
      float m = sv[0];
      int idx = colbase + c16;
#pragma unroll
      for (int nt = 1; nt < 4; ++nt) {
        if (sv[nt] > m) { m = sv[nt]; idx = colbase + nt * 16 + c16; }
      }
      for (int d = 1; d < 16; d <<= 1) {
        const float om = __shfl_xor(m, d, 64);
        const int oi = __shfl_xor(idx, d, 64);
        if (om > m || (om == m && oi < idx)) { m = om; idx = oi; }
      }
      float l = __expf(sv[0] - m) + __expf(sv[1] - m) + __expf(sv[2] - m) + __expf(sv[3] - m);
      for (int d = 1; d < 16; d <<= 1) l += __shfl_xor(l, d, 64);
      if (c16 == 0) {
        const int row = bm * BM + wm * 64 + mt * 16 + quad * 4 + r;
        pm[(size_t)row * NCHUNK + chunk] = m;     // row-major for coalesced combine
        pl[(size_t)row * NCHUNK + chunk] = l;
        pidx[(size_t)row * NCHUNK + chunk] = idx;
      }
    }
  }
}

// ---------- K2: per-row combine (128 threads = 128 chunks) + fused sy dot + ||c_y||^2 ----------
__global__ __launch_bounds__(128) void combine_kernel(
    const float* __restrict__ pm, const float* __restrict__ pl,
    const int* __restrict__ pidx, const float* __restrict__ x,
    const float* __restrict__ cent, const int* __restrict__ y,
    float* __restrict__ loss_part, float* __restrict__ corr_part) {
  const int row = blockIdx.x, t = threadIdx.x;  // t = chunk id, 0..127
  const int yc = y[row];

  float m = pm[(size_t)row * NCHUNK + t];
  float l = pl[(size_t)row * NCHUNK + t];
  int idx = pidx[(size_t)row * NCHUNK + t];

  const float4* xa = (const float4*)(x + (size_t)row * KDIM) + t * 2;
  const float4* ca = (const float4*)(cent + (size_t)yc * KDIM) + t * 2;
  const float4 a0 = xa[0], a1 = xa[1], b0 = ca[0], b1 = ca[1];
  float dot = a0.x * b0.x + a0.y * b0.y + a0.z * b0.z + a0.w * b0.w
            + a1.x * b1.x + a1.y * b1.y + a1.z * b1.z + a1.w * b1.w;
  float cc = b0.x * b0.x + b0.y * b0.y + b0.z * b0.z + b0.w * b0.w
           + b1.x * b1.x + b1.y * b1.y + b1.z * b1.z + b1.w * b1.w;

  // stage 1: butterfly max+argmax and dot/cc sums (no exps)
  float M = m;
  int gidx = idx;
  for (int d = 1; d < 64; d <<= 1) {
    const float om = __shfl_xor(M, d, 64);
    const int oi = __shfl_xor(gidx, d, 64);
    const float od = __shfl_xor(dot, d, 64);
    const float oc = __shfl_xor(cc, d, 64);
    if (om > M || (om == M && oi < gidx)) { M = om; gidx = oi; }
    dot += od;
    cc += oc;
  }
  __shared__ float sm[2], sd[2], sc[2];
  __shared__ int si[2];
  if ((t & 63) == 0) { sm[t >> 6] = M; si[t >> 6] = gidx; sd[t >> 6] = dot; sc[t >> 6] = cc; }
  __syncthreads();
  const float Mg = fmaxf(sm[0], sm[1]);
  // stage 2: single exp rescale, butterfly sum
  float lr = l * __expf(m - Mg);
  for (int d = 1; d < 64; d <<= 1) lr += __shfl_xor(lr, d, 64);
  __shared__ float sl[2];
  if ((t & 63) == 0) sl[t >> 6] = lr;
  __syncthreads();
  if (t == 0) {
    const float L = sl[0] + sl[1];
    int g;
    if (sm[1] > sm[0] || (sm[1] == sm[0] && si[1] < si[0])) g = si[1]; else g = si[0];
    const float sy = 2.0f * (sd[0] + sd[1]) - (sc[0] + sc[1]);
    loss_part[row] = __logf(L) + Mg - sy;
    corr_part[row] = (g == yc) ? 1.f : 0.f;
  }
}

// ---------- K3: finalize means ----------
__global__ __launch_bounds__(256) void finalize(const float* __restrict__ loss_part,
                                                const float* __restrict__ corr_part,
                                                float* __restrict__ out) {
  const int t = threadIdx.x;
  float s0 = 0.f, s1 = 0.f;
  for (int i = t; i < MDIM; i += 256) { s0 += loss_part[i]; s1 += corr_part[i]; }
  for (int d = 32; d; d >>= 1) {
    s0 += __shfl_down(s0, d, 64);
    s1 += __shfl_down(s1, d, 64);
  }
  __shared__ float r0[4], r1[4];
  if ((t & 63) == 0) { r0[t >> 6] = s0; r1[t >> 6] = s1; }
  __syncthreads();
  if (t == 0) {
    out[0] = (r0[0] + r0[1] + r0[2] + r0[3]) * (1.0f / MDIM);
    out[1] = (r1[0] + r1[1] + r1[2] + r1[3]) * (1.0f / MDIM);
  }
}

// ---------- launch ----------
extern "C" void kernel_launch(void* const* d_in, const int* in_sizes, int n_in,
                              void* d_out, int out_size, void* d_ws, size_t ws_size,
                              hipStream_t stream) {
  const float* x = (const float*)d_in[0];
  const int* y = (const int*)d_in[1];
  const float* cent = (const float*)d_in[2];
  float* out = (float*)d_out;

  char* ws = (char*)d_ws;
  const size_t OFF_PM = 0;                                   // 1 MB
  const size_t OFF_PL = OFF_PM + (size_t)NCHUNK * MDIM * 4;  // 1 MB
  const size_t OFF_PI = OFF_PL + (size_t)NCHUNK * MDIM * 4;  // 1 MB
  const size_t OFF_LP = OFF_PI + (size_t)NCHUNK * MDIM * 4;  // 8 KB
  const size_t OFF_CP = OFF_LP + (size_t)MDIM * 4;           // 8 KB
  const size_t NEED = OFF_CP + (size_t)MDIM * 4;
  if (ws_size < NEED) return;

  float* pm = (float*)(ws + OFF_PM);
  float* pl = (float*)(ws + OFF_PL);
  int* pidx = (int*)(ws + OFF_PI);
  float* loss_part = (float*)(ws + OFF_LP);
  float* corr_part = (float*)(ws + OFF_CP);

  gemm_fused<<<dim3(CDIM / BN, MDIM / BM), 256, 0, stream>>>(x, cent, pm, pl, pidx);
  combine_kernel<<<MDIM, 128, 0, stream>>>(pm, pl, pidx, x, cent, y, loss_part, corr_part);
  finalize<<<1, 256, 0, stream>>>(loss_part, corr_part, out);
}